// Round 4
// baseline (222.693 us; speedup 1.0000x reference)
//
#include <hip/hip_runtime.h>
#include <math.h>

#define ALPHA 32.0f
#define MRG 0.1f
#define STAT_WEIGHT 0.01f
#define STAT_ADJ_W 0.15f
#define COS_EPS 1e-8f

typedef __attribute__((ext_vector_type(8))) short bf16x8;
typedef __attribute__((ext_vector_type(4))) float f32x4;

__device__ __forceinline__ ushort f2bf(float f) {
    unsigned u = __float_as_uint(f);
    return (ushort)((u + 0x7FFFu + ((u >> 16) & 1u)) >> 16);   // RNE
}

// block-wide (128 threads = 2 waves) sum reduce, result broadcast to all
__device__ __forceinline__ float bred128(float v, float* sm, int d) {
    #pragma unroll
    for (int off = 1; off < 64; off <<= 1) v += __shfl_xor(v, off);
    if ((d & 63) == 0) sm[d >> 6] = v;
    __syncthreads();
    float r = sm[0] + sm[1];
    __syncthreads();
    return r;
}

// ---------------- K1: per-sample stats; writes Xn16 row b, adj[c], num_valid ---
// One block (128 threads) per sample b. Recomputes l2-norms on the fly (X is
// tiny); duplicate-class blocks write identical adj[c] (benign WAW).
__global__ void k_stats(const float* __restrict__ X, const float* __restrict__ proxies,
                        const float* __restrict__ cc, const int* __restrict__ T,
                        ushort* __restrict__ Xn16, float* __restrict__ adj,
                        float* __restrict__ scal, int B) {
    const int b = blockIdx.x, d = threadIdx.x;   // d in [0,128)
    __shared__ int Tl[512];
    __shared__ float sm[2];
    for (int i = d; i < B; i += 128) Tl[i] = T[i];
    __syncthreads();
    const int c = Tl[b];

    // censim(c): needs proxy row c and cc row c
    float p  = proxies[(size_t)c * 128 + d];
    float cv = cc[(size_t)c * 128 + d];
    float s2 = bred128(p * p, sm, d);
    float c2 = bred128(cv * cv, sm, d);
    float pc = bred128(p * cv, sm, d);

    // scan samples of class c (branch is block-uniform -> barrier-safe)
    float sd = 0.f, qd = 0.f;
    int cnt = 0, minj = -1;
    for (int j = 0; j < B; ++j) {
        if (Tl[j] == c) {
            float x = X[(size_t)j * 128 + d];
            float n2 = bred128(x * x, sm, d);
            float xn = x * rsqrtf(n2 + 1e-12f);
            sd += xn; qd += xn * xn;
            if (j == b) Xn16[(size_t)b * 128 + d] = f2bf(xn);
            if (minj < 0) minj = j;
            ++cnt;
        }
    }
    float fc = (float)cnt;
    float m = sd / fc;
    float var = fminf(fmaxf(qd / fc - m * m, 1e-6f), 10.0f);
    float sv = bred128(var, sm, d);
    if (d == 0) {
        float inv = rsqrtf(s2 + 1e-12f);
        float pn = fmaxf(sqrtf(s2) * inv, COS_EPS);
        float cn = fmaxf(sqrtf(c2), COS_EPS);
        float censim = (pc * inv) / (pn * cn);
        float vw = 1.0f / (1.0f + sv * (1.0f / 128.0f));
        adj[c] = censim * vw * STAT_ADJ_W;
        if (minj == b) atomicAdd(&scal[3], 1.0f);
    }
}

// ---------------- K2: GEMM + fused epilogue + cc-abs + finalize ----------------
// Block = 64 classes; wave wv owns classes [c0+wv*16, +16) -> bfr is 16 VGPRs
// (no spill). Wave sweeps all 512 rows; A read from L2-hot Xn16; no K-loop
// barriers. adj applied as per-class exp factor AFTER accumulation.
__launch_bounds__(256, 3)
__global__ void k_main(const float* __restrict__ proxies, const float* __restrict__ cc,
                       const ushort* __restrict__ Xn16, const int* __restrict__ T,
                       const float* __restrict__ adj, float* __restrict__ scal,
                       float* __restrict__ out, int C, int nblk) {
    const int tid = threadIdx.x, lane = tid & 63, wv = tid >> 6;
    const int nlo = lane & 15, quad = lane >> 4;
    const int c0 = blockIdx.x * 64;
    const int cls = c0 + wv * 16 + nlo;
    const bool valid = (cls < C);
    const int cl = valid ? cls : C - 1;

    // ---- cc |.| partial for this block's 64-class slice ----
    float cabs = 0.f;
    {
        const float4* cp = (const float4*)cc + (size_t)c0 * 32;
        const int lim = (c0 + 64 <= C ? 64 : C - c0) * 32;
        #pragma unroll
        for (int i = 0; i < 8; ++i) {
            int idx = i * 256 + tid;
            if (idx < lim) {
                float4 v = cp[idx];
                cabs += fabsf(v.x) + fabsf(v.y) + fabsf(v.z) + fabsf(v.w);
            }
        }
    }

    // ---- B fragments: normalize proxy row `cls` in-register -> bf16 ----
    bf16x8 bfr[4];
    {
        float4 pv[8];
        float s2 = 0.f;
        const float4* pr = (const float4*)(proxies + (size_t)cl * 128) + quad * 2;
        #pragma unroll
        for (int ks = 0; ks < 4; ++ks) {
            float4 a = pr[ks * 8], b = pr[ks * 8 + 1];
            pv[2 * ks] = a; pv[2 * ks + 1] = b;
            s2 += a.x*a.x + a.y*a.y + a.z*a.z + a.w*a.w
                + b.x*b.x + b.y*b.y + b.z*b.z + b.w*b.w;
        }
        s2 += __shfl_xor(s2, 16);
        s2 += __shfl_xor(s2, 32);
        float pin = rsqrtf(s2 + 1e-12f);
        #pragma unroll
        for (int ks = 0; ks < 4; ++ks) {
            float4 a = pv[2 * ks], b = pv[2 * ks + 1];
            bf16x8 f;
            f[0] = (short)f2bf(a.x * pin); f[1] = (short)f2bf(a.y * pin);
            f[2] = (short)f2bf(a.z * pin); f[3] = (short)f2bf(a.w * pin);
            f[4] = (short)f2bf(b.x * pin); f[5] = (short)f2bf(b.y * pin);
            f[6] = (short)f2bf(b.z * pin); f[7] = (short)f2bf(b.w * pin);
            bfr[ks] = f;
        }
    }

    // ---- sweep all 512 rows: 32 MFMA row-tiles, no barriers ----
    float pp = 0.f, np = 0.f;
    const ushort* xbase = Xn16 + (size_t)nlo * 128 + quad * 8;
    #pragma unroll 2
    for (int rt = 0; rt < 32; ++rt) {
        const ushort* xr = xbase + (size_t)rt * 16 * 128;
        bf16x8 a0 = *(const bf16x8*)(xr);
        bf16x8 a1 = *(const bf16x8*)(xr + 32);
        bf16x8 a2 = *(const bf16x8*)(xr + 64);
        bf16x8 a3 = *(const bf16x8*)(xr + 96);
        f32x4 acc = {0.f, 0.f, 0.f, 0.f};
        acc = __builtin_amdgcn_mfma_f32_16x16x32_bf16(a0, bfr[0], acc, 0, 0, 0);
        acc = __builtin_amdgcn_mfma_f32_16x16x32_bf16(a1, bfr[1], acc, 0, 0, 0);
        acc = __builtin_amdgcn_mfma_f32_16x16x32_bf16(a2, bfr[2], acc, 0, 0, 0);
        acc = __builtin_amdgcn_mfma_f32_16x16x32_bf16(a3, bfr[3], acc, 0, 0, 0);
        int4 tv = *(const int4*)(T + rt * 16 + quad * 4);
        int tvs[4] = {tv.x, tv.y, tv.z, tv.w};
        #pragma unroll
        for (int r = 0; r < 4; ++r) {
            bool pos = (tvs[r] == cls);
            float arg = pos ? (-ALPHA * (acc[r] - MRG)) : (ALPHA * (acc[r] + MRG));
            float e = __expf(arg);
            if (pos) pp += e; else np += e;
        }
    }

    // ---- per-class totals: sum over quads; apply adj factor; log1p ----
    pp += __shfl_xor(pp, 16); pp += __shfl_xor(pp, 32);
    np += __shfl_xor(np, 16); np += __shfl_xor(np, 32);
    float lp = 0.f, ln = 0.f;
    if (valid) {
        float av = adj[cls];
        lp = log1pf(pp * __expf(-ALPHA * av));
        ln = log1pf(np * __expf( ALPHA * av));
    }
    #pragma unroll
    for (int off = 1; off < 16; off <<= 1) {
        lp += __shfl_xor(lp, off);
        ln += __shfl_xor(ln, off);
    }
    #pragma unroll
    for (int off = 1; off < 64; off <<= 1) cabs += __shfl_xor(cabs, off);

    __shared__ float red[4][3];
    if (lane == 0) { red[wv][0] = lp; red[wv][1] = ln; red[wv][2] = cabs; }
    __syncthreads();
    if (tid == 0) {
        atomicAdd(&scal[0], red[0][0] + red[1][0] + red[2][0] + red[3][0]);
        atomicAdd(&scal[1], red[0][1] + red[1][1] + red[2][1] + red[3][1]);
        atomicAdd(&scal[2], red[0][2] + red[1][2] + red[2][2] + red[3][2]);
        __threadfence();
        unsigned old = atomicAdd((unsigned*)(scal + 4), 1u);
        if (old == (unsigned)(nblk - 1)) {
            // last block: all prior atomics visible (device-scope + fence)
            float S0 = atomicAdd(&scal[0], 0.f);
            float S1 = atomicAdd(&scal[1], 0.f);
            float S2 = atomicAdd(&scal[2], 0.f);
            float S3 = atomicAdd(&scal[3], 0.f);
            out[0] = S0 / S3 + S1 / (float)C + STAT_WEIGHT * (S2 / ((float)C * 128.f));
        }
    }
}

extern "C" void kernel_launch(void* const* d_in, const int* in_sizes, int n_in,
                              void* d_out, int out_size, void* d_ws, size_t ws_size,
                              hipStream_t stream) {
    const float* X       = (const float*)d_in[0];
    const int*   T       = (const int*)d_in[1];
    const float* proxies = (const float*)d_in[2];
    const float* cc      = (const float*)d_in[3];
    float* out = (float*)d_out;

    const int B = in_sizes[1];            // 512
    const int D = in_sizes[0] / B;        // 128
    const int C = in_sizes[2] / D;        // 50000

    float*  adj  = (float*)d_ws;                       // C fp32 (zeroed)
    float*  scal = adj + C;                            // 8 fp32 (zeroed)
    size_t  off  = (((size_t)C + 8) * 4 + 15) & ~(size_t)15;
    ushort* Xn16 = (ushort*)((char*)d_ws + off);       // B*D bf16

    const int nblk = (C + 63) / 64;

    hipMemsetAsync(adj, 0, ((size_t)C + 8) * sizeof(float), stream);
    k_stats<<<B, 128, 0, stream>>>(X, proxies, cc, T, Xn16, adj, scal, B);
    k_main<<<nblk, 256, 0, stream>>>(proxies, cc, Xn16, T, adj, scal, out, C, nblk);
}

// Round 6
// 219.183 us; speedup vs baseline: 1.0160x; 1.0160x over previous
//
#include <hip/hip_runtime.h>
#include <math.h>

#define ALPHA 32.0f
#define MRG 0.1f
#define STAT_WEIGHT 0.01f
#define STAT_ADJ_W 0.15f
#define COS_EPS 1e-8f

typedef __attribute__((ext_vector_type(8))) short bf16x8;
typedef __attribute__((ext_vector_type(4))) float f32x4;
typedef __attribute__((ext_vector_type(4))) unsigned int u32x4;

__device__ __forceinline__ ushort f2bf(float f) {
    unsigned u = __float_as_uint(f);
    return (ushort)((u + 0x7FFFu + ((u >> 16) & 1u)) >> 16);   // RNE
}

// pack two RNE bf16 into one u32 (low = a, high = b)
__device__ __forceinline__ unsigned pk2(float a, float b) {
    return (unsigned)f2bf(a) | ((unsigned)f2bf(b) << 16);
}

// block-wide (128 threads = 2 waves) sum reduce, result broadcast to all
__device__ __forceinline__ float bred128(float v, float* sm, int d) {
    #pragma unroll
    for (int off = 1; off < 64; off <<= 1) v += __shfl_xor(v, off);
    if ((d & 63) == 0) sm[d >> 6] = v;
    __syncthreads();
    float r = sm[0] + sm[1];
    __syncthreads();
    return r;
}

// ---------------- K1: per-sample stats; writes Xn16 row b, adj[c], num_valid ---
__global__ void k_stats(const float* __restrict__ X, const float* __restrict__ proxies,
                        const float* __restrict__ cc, const int* __restrict__ T,
                        ushort* __restrict__ Xn16, float* __restrict__ adj,
                        float* __restrict__ scal, int B) {
    const int b = blockIdx.x, d = threadIdx.x;   // d in [0,128)
    __shared__ int Tl[512];
    __shared__ float sm[2];
    for (int i = d; i < B; i += 128) Tl[i] = T[i];
    __syncthreads();
    const int c = Tl[b];

    float p  = proxies[(size_t)c * 128 + d];
    float cv = cc[(size_t)c * 128 + d];
    float s2 = bred128(p * p, sm, d);
    float c2 = bred128(cv * cv, sm, d);
    float pc = bred128(p * cv, sm, d);

    float sd = 0.f, qd = 0.f;
    int cnt = 0, minj = -1;
    for (int j = 0; j < B; ++j) {
        if (Tl[j] == c) {                      // block-uniform branch
            float x = X[(size_t)j * 128 + d];
            float n2 = bred128(x * x, sm, d);
            float xn = x * rsqrtf(n2 + 1e-12f);
            sd += xn; qd += xn * xn;
            if (j == b) Xn16[(size_t)b * 128 + d] = f2bf(xn);
            if (minj < 0) minj = j;
            ++cnt;
        }
    }
    float fc = (float)cnt;
    float m = sd / fc;
    float var = fminf(fmaxf(qd / fc - m * m, 1e-6f), 10.0f);
    float sv = bred128(var, sm, d);
    if (d == 0) {
        float inv = rsqrtf(s2 + 1e-12f);
        float pn = fmaxf(sqrtf(s2) * inv, COS_EPS);
        float cn = fmaxf(sqrtf(c2), COS_EPS);
        float censim = (pc * inv) / (pn * cn);
        float vw = 1.0f / (1.0f + sv * (1.0f / 128.0f));
        adj[c] = censim * vw * STAT_ADJ_W;
        if (minj == b) atomicAdd(&scal[3], 1.0f);
    }
}

// ---------------- K2: class-sweep GEMM, A resident in registers ----------------
// grid = 4 row-groups x 196 stripes (256 classes each), rowg fastest.
// Wave holds A for 32 rows (32 VGPRs) + T values; sweeps 16 class-tiles,
// normalizing B in-register (packed cvt) with 1-deep prefetch. Per-class
// pos/neg partials -> global atomics. cc-abs folded into rowg==0 blocks.
__launch_bounds__(256, 2)
__global__ void k_main(const float* __restrict__ proxies, const float* __restrict__ cc,
                       const ushort* __restrict__ Xn16, const int* __restrict__ T,
                       float* __restrict__ pos, float* __restrict__ neg,
                       float* __restrict__ scal, int C) {
    const int tid = threadIdx.x, lane = tid & 63, wv = tid >> 6;
    const int nlo = lane & 15, quad = lane >> 4;
    const int stripe = blockIdx.x >> 2, rowg = blockIdx.x & 3;
    const int cs = stripe * 256;
    const int rowbase = rowg * 128 + wv * 32;

    // A fragments: rows rowbase + rt*16 + nlo, k = ks*32 + quad*8 .. +8
    u32x4 afr[2][4];
    int tvs[2][4];
    #pragma unroll
    for (int rt = 0; rt < 2; ++rt) {
        const ushort* xr = Xn16 + (size_t)(rowbase + rt * 16 + nlo) * 128 + quad * 8;
        #pragma unroll
        for (int ks = 0; ks < 4; ++ks)
            afr[rt][ks] = *(const u32x4*)(xr + ks * 32);
        int4 t4 = *(const int4*)(T + rowbase + rt * 16 + quad * 4);
        tvs[rt][0] = t4.x; tvs[rt][1] = t4.y; tvs[rt][2] = t4.z; tvs[rt][3] = t4.w;
    }

    // cc |.| partial for this stripe (rowg 0 only)
    float cabs = 0.f;
    if (rowg == 0) {
        int n4 = (cs + 256 <= C ? 256 : C - cs) * 32;
        const float4* cp = (const float4*)(cc + (size_t)cs * 128);
        for (int i = tid; i < n4; i += 256) {
            float4 v = cp[i];
            cabs += fabsf(v.x) + fabsf(v.y) + fabsf(v.z) + fabsf(v.w);
        }
    }

    // sweep 16 class-tiles with 1-deep prefetch of proxy rows
    float4 pv[8], nx[8];
    {
        int br = cs + nlo; if (br >= C) br = C - 1;
        const float4* pr = (const float4*)(proxies + (size_t)br * 128) + quad * 2;
        #pragma unroll
        for (int ks = 0; ks < 4; ++ks) { pv[2*ks] = pr[ks*8]; pv[2*ks+1] = pr[ks*8+1]; }
    }
    #pragma unroll 2
    for (int ct = 0; ct < 16; ++ct) {
        if (ct < 15) {
            int br = cs + (ct + 1) * 16 + nlo; if (br >= C) br = C - 1;
            const float4* pr = (const float4*)(proxies + (size_t)br * 128) + quad * 2;
            #pragma unroll
            for (int ks = 0; ks < 4; ++ks) { nx[2*ks] = pr[ks*8]; nx[2*ks+1] = pr[ks*8+1]; }
        }
        float s2 = 0.f;
        #pragma unroll
        for (int j = 0; j < 8; ++j) {
            float4 v = pv[j];
            s2 += v.x*v.x + v.y*v.y + v.z*v.z + v.w*v.w;
        }
        s2 += __shfl_xor(s2, 16);
        s2 += __shfl_xor(s2, 32);
        float pin = rsqrtf(s2 + 1e-12f);

        f32x4 acc0 = {0.f,0.f,0.f,0.f}, acc1 = {0.f,0.f,0.f,0.f};
        #pragma unroll
        for (int ks = 0; ks < 4; ++ks) {
            float4 a = pv[2*ks], b = pv[2*ks+1];
            u32x4 u;
            u.x = pk2(a.x * pin, a.y * pin);
            u.y = pk2(a.z * pin, a.w * pin);
            u.z = pk2(b.x * pin, b.y * pin);
            u.w = pk2(b.z * pin, b.w * pin);
            bf16x8 bfr = __builtin_bit_cast(bf16x8, u);
            acc0 = __builtin_amdgcn_mfma_f32_16x16x32_bf16(
                       __builtin_bit_cast(bf16x8, afr[0][ks]), bfr, acc0, 0, 0, 0);
            acc1 = __builtin_amdgcn_mfma_f32_16x16x32_bf16(
                       __builtin_bit_cast(bf16x8, afr[1][ks]), bfr, acc1, 0, 0, 0);
        }

        int cls = cs + ct * 16 + nlo;
        bool valid = (cls < C);
        float pp = 0.f, np = 0.f;
        #pragma unroll
        for (int r = 0; r < 4; ++r) {
            { bool po = (tvs[0][r] == cls); float v = acc0[r];
              float e = __expf(po ? -ALPHA * (v - MRG) : ALPHA * (v + MRG));
              pp += po ? e : 0.f; np += po ? 0.f : e; }
            { bool po = (tvs[1][r] == cls); float v = acc1[r];
              float e = __expf(po ? -ALPHA * (v - MRG) : ALPHA * (v + MRG));
              pp += po ? e : 0.f; np += po ? 0.f : e; }
        }
        pp += __shfl_xor(pp, 16); pp += __shfl_xor(pp, 32);
        np += __shfl_xor(np, 16); np += __shfl_xor(np, 32);
        if (quad == 0 && valid) {
            atomicAdd(&pos[cls], pp);
            atomicAdd(&neg[cls], np);
        }
        #pragma unroll
        for (int j = 0; j < 8; ++j) pv[j] = nx[j];
    }

    if (rowg == 0) {
        #pragma unroll
        for (int off = 1; off < 64; off <<= 1) cabs += __shfl_xor(cabs, off);
        __shared__ float smc[4];
        if (lane == 0) smc[wv] = cabs;
        __syncthreads();
        if (tid == 0) atomicAdd(&scal[2], smc[0] + smc[1] + smc[2] + smc[3]);
    }
}

// ---------------- K3: per-class log1p + finalize -------------------------------
__global__ void k_fin(const float* __restrict__ pos, const float* __restrict__ neg,
                      const float* __restrict__ adj, float* __restrict__ scal,
                      float* __restrict__ out, int C, int nblk) {
    const int tid = threadIdx.x, lane = tid & 63, wv = tid >> 6;
    const int c = blockIdx.x * 256 + tid;
    float lp = 0.f, ln = 0.f;
    if (c < C) {
        float a = adj[c];
        lp = log1pf(pos[c] * __expf(-ALPHA * a));   // pos[c]==0 for empty -> 0
        ln = log1pf(neg[c] * __expf( ALPHA * a));
    }
    #pragma unroll
    for (int off = 1; off < 64; off <<= 1) {
        lp += __shfl_xor(lp, off);
        ln += __shfl_xor(ln, off);
    }
    __shared__ float sm[4][2];
    if (lane == 0) { sm[wv][0] = lp; sm[wv][1] = ln; }
    __syncthreads();
    if (tid == 0) {
        atomicAdd(&scal[0], sm[0][0] + sm[1][0] + sm[2][0] + sm[3][0]);
        atomicAdd(&scal[1], sm[0][1] + sm[1][1] + sm[2][1] + sm[3][1]);
        __threadfence();
        unsigned old = atomicAdd((unsigned*)(scal + 5), 1u);
        if (old == (unsigned)(nblk - 1)) {
            float S0 = atomicAdd(&scal[0], 0.f);
            float S1 = atomicAdd(&scal[1], 0.f);
            float S2 = atomicAdd(&scal[2], 0.f);
            float S3 = atomicAdd(&scal[3], 0.f);
            out[0] = S0 / S3 + S1 / (float)C + STAT_WEIGHT * (S2 / ((float)C * 128.f));
        }
    }
}

extern "C" void kernel_launch(void* const* d_in, const int* in_sizes, int n_in,
                              void* d_out, int out_size, void* d_ws, size_t ws_size,
                              hipStream_t stream) {
    const float* X       = (const float*)d_in[0];
    const int*   T       = (const int*)d_in[1];
    const float* proxies = (const float*)d_in[2];
    const float* cc      = (const float*)d_in[3];
    float* out = (float*)d_out;

    const int B = in_sizes[1];            // 512
    const int D = in_sizes[0] / B;        // 128
    const int C = in_sizes[2] / D;        // 50000

    float*  pos  = (float*)d_ws;                       // C
    float*  neg  = pos + C;                            // C
    float*  adj  = neg + C;                            // C
    float*  scal = adj + C;                            // 8
    ushort* Xn16 = (ushort*)(scal + 8);                // B*D bf16

    const int nstripe = (C + 255) / 256;               // 196
    const int nfin    = (C + 255) / 256;               // 196

    (void)hipMemsetAsync(pos, 0, ((size_t)3 * C + 8) * sizeof(float), stream);
    k_stats<<<B, 128, 0, stream>>>(X, proxies, cc, T, Xn16, adj, scal, B);
    k_main<<<nstripe * 4, 256, 0, stream>>>(proxies, cc, Xn16, T, pos, neg, scal, C);
    k_fin<<<nfin, 256, 0, stream>>>(pos, neg, adj, scal, out, C, nfin);
}

// Round 7
// 175.687 us; speedup vs baseline: 1.2676x; 1.2476x over previous
//
#include <hip/hip_runtime.h>
#include <math.h>

#define ALPHA 32.0f
#define MRG 0.1f
#define STAT_WEIGHT 0.01f
#define STAT_ADJ_W 0.15f
#define COS_EPS 1e-8f

typedef __attribute__((ext_vector_type(8))) short bf16x8;
typedef __attribute__((ext_vector_type(4))) float f32x4;
typedef __attribute__((ext_vector_type(4))) unsigned int u32x4;

__device__ __forceinline__ ushort f2bf(float f) {
    unsigned u = __float_as_uint(f);
    return (ushort)((u + 0x7FFFu + ((u >> 16) & 1u)) >> 16);   // RNE
}
__device__ __forceinline__ unsigned pk2(float a, float b) {
    return (unsigned)f2bf(a) | ((unsigned)f2bf(b) << 16);
}

// block-wide (128 threads = 2 waves) sum reduce, result broadcast to all
__device__ __forceinline__ float bred128(float v, float* sm, int d) {
    #pragma unroll
    for (int off = 1; off < 64; off <<= 1) v += __shfl_xor(v, off);
    if ((d & 63) == 0) sm[d >> 6] = v;
    __syncthreads();
    float r = sm[0] + sm[1];
    __syncthreads();
    return r;
}

// ---------------- K1: per-sample stats; writes Xn16 row b, adj[c], num_valid ---
__global__ void k_stats(const float* __restrict__ X, const float* __restrict__ proxies,
                        const float* __restrict__ cc, const int* __restrict__ T,
                        ushort* __restrict__ Xn16, float* __restrict__ adj,
                        float* __restrict__ scal, int B) {
    const int b = blockIdx.x, d = threadIdx.x;   // d in [0,128)
    __shared__ int Tl[512];
    __shared__ float sm[2];
    for (int i = d; i < B; i += 128) Tl[i] = T[i];
    __syncthreads();
    const int c = Tl[b];

    float p  = proxies[(size_t)c * 128 + d];
    float cv = cc[(size_t)c * 128 + d];
    float s2 = bred128(p * p, sm, d);
    float c2 = bred128(cv * cv, sm, d);
    float pc = bred128(p * cv, sm, d);

    float sd = 0.f, qd = 0.f;
    int cnt = 0, minj = -1;
    for (int j = 0; j < B; ++j) {
        if (Tl[j] == c) {                      // block-uniform branch
            float x = X[(size_t)j * 128 + d];
            float n2 = bred128(x * x, sm, d);
            float xn = x * rsqrtf(n2 + 1e-12f);
            sd += xn; qd += xn * xn;
            if (j == b) Xn16[(size_t)b * 128 + d] = f2bf(xn);
            if (minj < 0) minj = j;
            ++cnt;
        }
    }
    float fc = (float)cnt;
    float m = sd / fc;
    float var = fminf(fmaxf(qd / fc - m * m, 1e-6f), 10.0f);
    float sv = bred128(var, sm, d);
    if (d == 0) {
        float inv = rsqrtf(s2 + 1e-12f);
        float pn = fmaxf(sqrtf(s2) * inv, COS_EPS);
        float cn = fmaxf(sqrtf(c2), COS_EPS);
        float censim = (pc * inv) / (pn * cn);
        float vw = 1.0f / (1.0f + sv * (1.0f / 128.0f));
        adj[c] = censim * vw * STAT_ADJ_W;
        if (minj == b) atomicAdd(&scal[3], 1.0f);
    }
}

// ---------------- K2: orientation-A GEMM, all-register, full fuse --------------
// 391 blocks x 128 classes. Wave owns 32 classes (bfr[2][4]=32 VGPRs), sweeps
// all 512 rows (32 tiles x 8 MFMAs, two indep acc chains). No K-loop barriers,
// no prefetch buffers (spill lesson r3/r6). pos/neg complete in-block ->
// log1p here; adj via post-hoc exp factor with present-gate (no adj memset).
__launch_bounds__(256, 2)
__global__ void k_main(const float* __restrict__ proxies, const float* __restrict__ cc,
                       const ushort* __restrict__ Xn16, const int* __restrict__ T,
                       const float* __restrict__ adj, float* __restrict__ scal,
                       float* __restrict__ out, int C, int nblk) {
    const int tid = threadIdx.x, lane = tid & 63, wv = tid >> 6;
    const int nlo = lane & 15, quad = lane >> 4;
    const int c0 = blockIdx.x * 128;

    __shared__ int Tl[512];
    __shared__ float red[4][3];
    Tl[tid] = T[tid];
    Tl[tid + 256] = T[tid + 256];

    // ---- cc |.| partial for this block's 128-class slice ----
    float cabs = 0.f;
    {
        const int n4 = ((c0 + 128 <= C) ? 128 : (C - c0)) * 32;
        const float4* cp = (const float4*)(cc + (size_t)c0 * 128);
        for (int i = tid; i < n4; i += 256) {
            float4 v = cp[i];
            cabs += fabsf(v.x) + fabsf(v.y) + fabsf(v.z) + fabsf(v.w);
        }
    }

    // ---- B fragments: normalize 2x16 proxy rows in-register -> bf16 ----
    // lane (nlo,quad) loads row cls slices k = ks*32+quad*8..+8 (exactly its
    // MFMA B-fragment), shfl-reduces the row norm across quads.
    bf16x8 bfr[2][4];
    #pragma unroll
    for (int t = 0; t < 2; ++t) {
        int cls = c0 + wv * 32 + t * 16 + nlo;
        int cl = (cls < C) ? cls : C - 1;
        const float4* pr = (const float4*)(proxies + (size_t)cl * 128);
        float4 v0[4], v1[4];
        float s2 = 0.f;
        #pragma unroll
        for (int ks = 0; ks < 4; ++ks) {
            v0[ks] = pr[ks * 8 + quad * 2];
            v1[ks] = pr[ks * 8 + quad * 2 + 1];
            s2 += v0[ks].x*v0[ks].x + v0[ks].y*v0[ks].y + v0[ks].z*v0[ks].z + v0[ks].w*v0[ks].w
                + v1[ks].x*v1[ks].x + v1[ks].y*v1[ks].y + v1[ks].z*v1[ks].z + v1[ks].w*v1[ks].w;
        }
        s2 += __shfl_xor(s2, 16);
        s2 += __shfl_xor(s2, 32);
        float pin = rsqrtf(s2 + 1e-12f);
        #pragma unroll
        for (int ks = 0; ks < 4; ++ks) {
            u32x4 u;
            u.x = pk2(v0[ks].x * pin, v0[ks].y * pin);
            u.y = pk2(v0[ks].z * pin, v0[ks].w * pin);
            u.z = pk2(v1[ks].x * pin, v1[ks].y * pin);
            u.w = pk2(v1[ks].z * pin, v1[ks].w * pin);
            bfr[t][ks] = __builtin_bit_cast(bf16x8, u);
        }
    }
    __syncthreads();   // Tl ready

    // ---- sweep all 512 rows ----
    float pp0 = 0.f, pp1 = 0.f, np0 = 0.f, np1 = 0.f;
    const int cls0 = c0 + wv * 32 + nlo;
    const int cls1 = cls0 + 16;
    const ushort* xbase = Xn16 + (size_t)nlo * 128 + quad * 8;
    #pragma unroll 2
    for (int rt = 0; rt < 32; ++rt) {
        const ushort* xr = xbase + (size_t)rt * 16 * 128;
        u32x4 af0 = *(const u32x4*)(xr);
        u32x4 af1 = *(const u32x4*)(xr + 32);
        u32x4 af2 = *(const u32x4*)(xr + 64);
        u32x4 af3 = *(const u32x4*)(xr + 96);
        f32x4 acc0 = {0.f,0.f,0.f,0.f}, acc1 = {0.f,0.f,0.f,0.f};
        acc0 = __builtin_amdgcn_mfma_f32_16x16x32_bf16(__builtin_bit_cast(bf16x8, af0), bfr[0][0], acc0, 0, 0, 0);
        acc1 = __builtin_amdgcn_mfma_f32_16x16x32_bf16(__builtin_bit_cast(bf16x8, af0), bfr[1][0], acc1, 0, 0, 0);
        acc0 = __builtin_amdgcn_mfma_f32_16x16x32_bf16(__builtin_bit_cast(bf16x8, af1), bfr[0][1], acc0, 0, 0, 0);
        acc1 = __builtin_amdgcn_mfma_f32_16x16x32_bf16(__builtin_bit_cast(bf16x8, af1), bfr[1][1], acc1, 0, 0, 0);
        acc0 = __builtin_amdgcn_mfma_f32_16x16x32_bf16(__builtin_bit_cast(bf16x8, af2), bfr[0][2], acc0, 0, 0, 0);
        acc1 = __builtin_amdgcn_mfma_f32_16x16x32_bf16(__builtin_bit_cast(bf16x8, af2), bfr[1][2], acc1, 0, 0, 0);
        acc0 = __builtin_amdgcn_mfma_f32_16x16x32_bf16(__builtin_bit_cast(bf16x8, af3), bfr[0][3], acc0, 0, 0, 0);
        acc1 = __builtin_amdgcn_mfma_f32_16x16x32_bf16(__builtin_bit_cast(bf16x8, af3), bfr[1][3], acc1, 0, 0, 0);

        int4 t4 = *(const int4*)&Tl[rt * 16 + quad * 4];
        int tvs[4] = {t4.x, t4.y, t4.z, t4.w};
        #pragma unroll
        for (int r = 0; r < 4; ++r) {
            { bool po = (tvs[r] == cls0); float v = acc0[r];
              float e = __expf(po ? -ALPHA * (v - MRG) : ALPHA * (v + MRG));
              pp0 += po ? e : 0.f; np0 += po ? 0.f : e; }
            { bool po = (tvs[r] == cls1); float v = acc1[r];
              float e = __expf(po ? -ALPHA * (v - MRG) : ALPHA * (v + MRG));
              pp1 += po ? e : 0.f; np1 += po ? 0.f : e; }
        }
    }

    // ---- per-class totals across quads; adj factor; log1p ----
    pp0 += __shfl_xor(pp0, 16); pp0 += __shfl_xor(pp0, 32);
    np0 += __shfl_xor(np0, 16); np0 += __shfl_xor(np0, 32);
    pp1 += __shfl_xor(pp1, 16); pp1 += __shfl_xor(pp1, 32);
    np1 += __shfl_xor(np1, 16); np1 += __shfl_xor(np1, 32);

    float lp = 0.f, ln = 0.f;
    {
        float a0 = adj[(cls0 < C) ? cls0 : C - 1];   // garbage-safe: selected below
        float a1 = adj[(cls1 < C) ? cls1 : C - 1];
        float as0 = (pp0 > 0.f) ? a0 : 0.f;          // absent class => adj = 0
        float as1 = (pp1 > 0.f) ? a1 : 0.f;
        if (cls0 < C) {
            lp += log1pf(pp0 * __expf(-ALPHA * as0));
            ln += log1pf(np0 * __expf( ALPHA * as0));
        }
        if (cls1 < C) {
            lp += log1pf(pp1 * __expf(-ALPHA * as1));
            ln += log1pf(np1 * __expf( ALPHA * as1));
        }
    }
    // all quads hold identical (lp,ln); reduce within 16-lane group, lane 0 wins
    #pragma unroll
    for (int off = 1; off < 16; off <<= 1) {
        lp += __shfl_xor(lp, off);
        ln += __shfl_xor(ln, off);
    }
    #pragma unroll
    for (int off = 1; off < 64; off <<= 1) cabs += __shfl_xor(cabs, off);

    if (lane == 0) { red[wv][0] = lp; red[wv][1] = ln; red[wv][2] = cabs; }
    __syncthreads();
    if (tid == 0) {
        atomicAdd(&scal[0], red[0][0] + red[1][0] + red[2][0] + red[3][0]);
        atomicAdd(&scal[1], red[0][1] + red[1][1] + red[2][1] + red[3][1]);
        atomicAdd(&scal[2], red[0][2] + red[1][2] + red[2][2] + red[3][2]);
        __threadfence();
        unsigned old = atomicAdd((unsigned*)(scal + 4), 1u);
        if (old == (unsigned)(nblk - 1)) {
            float S0 = atomicAdd(&scal[0], 0.f);
            float S1 = atomicAdd(&scal[1], 0.f);
            float S2 = atomicAdd(&scal[2], 0.f);
            float S3 = atomicAdd(&scal[3], 0.f);
            out[0] = S0 / S3 + S1 / (float)C + STAT_WEIGHT * (S2 / ((float)C * 128.f));
        }
    }
}

extern "C" void kernel_launch(void* const* d_in, const int* in_sizes, int n_in,
                              void* d_out, int out_size, void* d_ws, size_t ws_size,
                              hipStream_t stream) {
    const float* X       = (const float*)d_in[0];
    const int*   T       = (const int*)d_in[1];
    const float* proxies = (const float*)d_in[2];
    const float* cc      = (const float*)d_in[3];
    float* out = (float*)d_out;

    const int B = in_sizes[1];            // 512
    const int D = in_sizes[0] / B;        // 128
    const int C = in_sizes[2] / D;        // 50000

    float*  adj  = (float*)d_ws;                       // C (only present classes written/read)
    float*  scal = adj + C;                            // 8 (zeroed)
    ushort* Xn16 = (ushort*)(scal + 8);                // B*D bf16

    const int nblk = (C + 127) / 128;                  // 391

    (void)hipMemsetAsync(scal, 0, 8 * sizeof(float), stream);
    k_stats<<<B, 128, 0, stream>>>(X, proxies, cc, T, Xn16, adj, scal, B);
    k_main<<<nblk, 256, 0, stream>>>(proxies, cc, Xn16, T, adj, scal, out, C, nblk);
}